// Round 1
// baseline (90.547 us; speedup 1.0000x reference)
//
#include <hip/hip_runtime.h>

typedef __attribute__((ext_vector_type(8))) __bf16 bf16x8;
typedef __attribute__((ext_vector_type(4))) __bf16 bf16x4;
typedef __attribute__((ext_vector_type(4))) float f32x4;

#define D_IN 128
#define N_OUT 32
#define K129 129
#define WROW 16512   // 128*129 floats per output row of W
#define BM 64        // rows per block
#define CPG 8        // chunks (o values) per o-group; 4 groups of 8 = 32 outputs

// Prep: quadratic part of W -> bf16 [4096][128] in workspace.
// W2[o*128+i][j] = W[o, i*129+j]  (each row = 128 contiguous floats in W)
__global__ void prep_w(const float* __restrict__ W, __bf16* __restrict__ Wq) {
    int base = blockIdx.x * 2048;
    for (int it = 0; it < 8; ++it) {
        int idx = base + it * 256 + threadIdx.x;   // 0..524287, coalesced in j
        int oi = idx >> 7;
        int j  = idx & 127;
        int o = oi >> 7, i = oi & 127;
        Wq[idx] = (__bf16)W[o * WROW + i * K129 + j];
    }
}

__global__ __launch_bounds__(256) void quad_main(
    const float* __restrict__ x, const float* __restrict__ W,
    const __bf16* __restrict__ Wq, int usePrep,
    const float* __restrict__ bias, float* __restrict__ out) {

    // +8 bf16 pad per row: keeps 16B alignment for b128 ops, breaks 256B-stride bank conflict
    __shared__ __bf16 xa[64][136];    // A tile: x rows (bf16)
    __shared__ __bf16 wb[128][136];   // B tile: W2 rows for current o
    __shared__ float  wlin[128];      // W[o, i*129+128] (xe=1 column)

    const int tid  = threadIdx.x;
    const int lane = tid & 63;
    const int wave = tid >> 6;        // 0..3, each owns a 16-row stripe
    const int c15  = lane & 15;       // MFMA row/col within tile
    const int kg   = lane >> 4;       // k-group 0..3
    const int mblk = blockIdx.x & 255;
    const int og   = blockIdx.x >> 8; // 0..3
    const long row0 = (long)mblk * BM;

    // ---- stage x tile: 64 rows x 128 f32 -> bf16 LDS ----
    {
        int r = tid >> 2, q = tid & 3;
        const float4* src = reinterpret_cast<const float4*>(x + (row0 + r) * D_IN + q * 32);
        for (int k4 = 0; k4 < 8; ++k4) {
            float4 v = src[k4];
            bf16x4 p = { (__bf16)v.x, (__bf16)v.y, (__bf16)v.z, (__bf16)v.w };
            *reinterpret_cast<bf16x4*>(&xa[r][q * 32 + k4 * 4]) = p;
        }
    }

    // ---- preload epilogue x factors (exact fp32), hoisted out of chunk loop ----
    // xf[ct][r] = x[row(r), i = ct*16 + c15], row(r) = row0 + wave*16 + kg*4 + r
    float xf[8][4];
    for (int ct = 0; ct < 8; ++ct)
        for (int r = 0; r < 4; ++r)
            xf[ct][r] = x[(row0 + wave * 16 + kg * 4 + r) * D_IN + ct * 16 + c15];

    for (int c = 0; c < CPG; ++c) {
        const int o = og * CPG + c;

        __syncthreads();   // previous chunk's readers done (covers xa staging on iter 0)

        // ---- stage W chunk: rows n = o*128+i, cols j=0..127, as bf16 ----
        if (usePrep) {
            int r = tid >> 1, h = tid & 1;
            const bf16x8* src = reinterpret_cast<const bf16x8*>(Wq + ((size_t)(o * 128 + r)) * 128 + h * 64);
            for (int e = 0; e < 8; ++e)
                *reinterpret_cast<bf16x8*>(&wb[r][h * 64 + e * 8]) = src[e];
        } else {
            for (int it = 0; it < 64; ++it) {
                int idx = it * 256 + tid;
                int r = idx >> 7, col = idx & 127;
                wb[r][col] = (__bf16)W[o * WROW + r * K129 + col];
            }
        }
        if (tid < 128) wlin[tid] = W[o * WROW + tid * K129 + 128];
        __syncthreads();

        // ---- MFMA: H-tile rows = wave's 16 rows, cols = 128 (8 col-tiles), K=128 ----
        f32x4 acc[8];
        for (int ct = 0; ct < 8; ++ct) acc[ct] = (f32x4){0.f, 0.f, 0.f, 0.f};
        for (int ks = 0; ks < 4; ++ks) {
            bf16x8 af = *reinterpret_cast<const bf16x8*>(&xa[wave * 16 + c15][ks * 32 + kg * 8]);
            for (int ct = 0; ct < 8; ++ct) {
                bf16x8 bfr = *reinterpret_cast<const bf16x8*>(&wb[ct * 16 + c15][ks * 32 + kg * 8]);
                acc[ct] = __builtin_amdgcn_mfma_f32_16x16x32_bf16(af, bfr, acc[ct], 0, 0, 0);
            }
        }

        // ---- fused epilogue: y[row,o] = sum_i (H + wlin_i) * x[row,i]  + bias ----
        // acc[ct][r] = H[row = wave*16 + kg*4 + r][i = ct*16 + c15]
        float s[4] = {0.f, 0.f, 0.f, 0.f};
        for (int ct = 0; ct < 8; ++ct) {
            float wl = wlin[ct * 16 + c15];
            for (int r = 0; r < 4; ++r)
                s[r] += (acc[ct][r] + wl) * xf[ct][r];
        }
        // reduce over the 16 column-lanes (bits 0..3 of lane)
        for (int d = 1; d < 16; d <<= 1)
            for (int r = 0; r < 4; ++r)
                s[r] += __shfl_xor(s[r], d);

        if (c15 == 0) {
            float bo = bias[o];
            for (int r = 0; r < 4; ++r)
                out[(row0 + wave * 16 + kg * 4 + r) * N_OUT + o] = s[r] + bo;
        }
    }
}

extern "C" void kernel_launch(void* const* d_in, const int* in_sizes, int n_in,
                              void* d_out, int out_size, void* d_ws, size_t ws_size,
                              hipStream_t stream) {
    const float* x    = (const float*)d_in[0];
    const float* W    = (const float*)d_in[1];
    const float* bias = (const float*)d_in[2];
    float* out = (float*)d_out;

    __bf16* Wq = (__bf16*)d_ws;
    int usePrep = (ws_size >= (size_t)4096 * 128 * sizeof(__bf16)) ? 1 : 0;

    if (usePrep) prep_w<<<256, 256, 0, stream>>>(W, Wq);
    // grid: 256 m-blocks (64 rows each) x 4 o-groups (8 outputs each)
    quad_main<<<1024, 256, 0, stream>>>(x, W, Wq, usePrep, bias, out);
}

// Round 2
// 56.466 us; speedup vs baseline: 1.6036x; 1.6036x over previous
//
#include <hip/hip_runtime.h>

typedef __attribute__((ext_vector_type(8)))  __bf16 bf16x8;
typedef __attribute__((ext_vector_type(4)))  __bf16 bf16x4;
typedef __attribute__((ext_vector_type(16))) float  f32x16;

#define D_IN  128
#define N_OUT 32
#define K129  129
#define WROW  16512          // 128*129 floats per W row
#define KE    144            // extended K: 128 + 16 (col 128 = ones/wlin, rest 0)
#define KS_N  9              // KE / 16 k-steps for 32x32x16
#define XQ_ELEMS (16384 * KE)
#define WQ_ELEMS (32 * 128 * KE)

// ---- prep: x -> x~ bf16 [16384][144]  (col 128 = 1.0, 129..143 = 0) ----
__global__ void prep_x(const float* __restrict__ x, __bf16* __restrict__ xq) {
    for (int e = blockIdx.x * 256 + threadIdx.x; e < XQ_ELEMS; e += gridDim.x * 256) {
        int row = e / KE, col = e - row * KE;
        float v = 0.f;
        if (col < D_IN) v = x[row * D_IN + col];
        else if (col == D_IN) v = 1.f;
        xq[e] = (__bf16)v;
    }
}

// ---- prep: W -> Wq~ bf16 [32][128][144]  ([o][i][128] = wlin, 129..143 = 0) ----
__global__ void prep_w(const float* __restrict__ W, __bf16* __restrict__ Wq) {
    for (int e = blockIdx.x * 256 + threadIdx.x; e < WQ_ELEMS; e += gridDim.x * 256) {
        int oi = e / KE, k = e - oi * KE;       // oi = o*128 + i
        int o = oi >> 7, i = oi & 127;
        float v = 0.f;
        if (k < D_IN) v = W[o * WROW + i * K129 + k];
        else if (k == D_IN) v = W[o * WROW + i * K129 + D_IN];
        Wq[e] = (__bf16)v;
    }
}

// Load one m-tile's B fragments (x rows as MFMA B operand) + epilogue xe chunks.
// B frag (32x32x16): lane l -> col b = l&31, k = (l>>5)*8 + r  (contiguous 8 bf16).
// xe chunk (ct,q): 4 bf16 at i = (sub*2+ct)*32 + q*8 + (l>>5)*4  (matches C-layout rows).
template<int PREP>
__device__ __forceinline__ void load_tile(
    bf16x8 (&B)[KS_N], bf16x4 (&X)[2][4],
    const __bf16* __restrict__ xq, const float* __restrict__ x,
    long row, int sub, int hi)
{
    if (PREP) {
        const __bf16* xr = xq + row * KE;
        #pragma unroll
        for (int ks = 0; ks < KS_N; ++ks)
            B[ks] = *reinterpret_cast<const bf16x8*>(xr + ks * 16 + hi * 8);
        #pragma unroll
        for (int ct = 0; ct < 2; ++ct)
            #pragma unroll
            for (int q = 0; q < 4; ++q)
                X[ct][q] = *reinterpret_cast<const bf16x4*>(xr + (sub * 2 + ct) * 32 + q * 8 + hi * 4);
    } else {
        const float* xr = x + row * D_IN;
        #pragma unroll
        for (int ks = 0; ks < 8; ++ks) {
            bf16x8 f;
            #pragma unroll
            for (int r = 0; r < 8; ++r) f[r] = (__bf16)xr[ks * 16 + hi * 8 + r];
            B[ks] = f;
        }
        bf16x8 z;
        #pragma unroll
        for (int r = 0; r < 8; ++r) z[r] = (__bf16)0.f;
        if (hi == 0) z[0] = (__bf16)1.0f;      // x~[.,128] = 1
        B[8] = z;
        #pragma unroll
        for (int ct = 0; ct < 2; ++ct)
            #pragma unroll
            for (int q = 0; q < 4; ++q) {
                bf16x4 t;
                #pragma unroll
                for (int j = 0; j < 4; ++j)
                    t[j] = (__bf16)xr[(sub * 2 + ct) * 32 + q * 8 + hi * 4 + j];
                X[ct][q] = t;
            }
    }
}

// One m-tile: prefetch next tile's frags, 18 MFMA, in-lane epilogue dot,
// shfl hi-combine, LDS pair-combine, store. BC/XC = current regs, BN/XN = next.
#define STEP(MT, BC, XC, BN, XN)                                                   \
  {                                                                                \
    long b0 = rbase + (long)(MT) * 32;                                             \
    if ((MT) + 1 < 16)                                                             \
      load_tile<PREP>(BN, XN, xq, x, rbase + (long)((MT) + 1) * 32 + b32, sub, hi);\
    f32x16 a0, a1;                                                                 \
    _Pragma("unroll")                                                              \
    for (int r = 0; r < 16; ++r) { a0[r] = 0.f; a1[r] = 0.f; }                     \
    _Pragma("unroll")                                                              \
    for (int ks = 0; ks < KS_N; ++ks) {                                            \
      a0 = __builtin_amdgcn_mfma_f32_32x32x16_bf16(A[0][ks], BC[ks], a0, 0, 0, 0); \
      a1 = __builtin_amdgcn_mfma_f32_32x32x16_bf16(A[1][ks], BC[ks], a1, 0, 0, 0); \
    }                                                                              \
    float s = 0.f;                                                                 \
    _Pragma("unroll")                                                              \
    for (int q = 0; q < 4; ++q)                                                    \
      _Pragma("unroll")                                                            \
      for (int j = 0; j < 4; ++j) {                                                \
        s += a0[q * 4 + j] * (float)XC[0][q][j];                                   \
        s += a1[q * 4 + j] * (float)XC[1][q][j];                                   \
      }                                                                            \
    s += __shfl_xor(s, 32);                                                        \
    if (hi == 0) red[(MT) & 1][pairId][sub][b32] = s;                              \
    __syncthreads();                                                               \
    if (sub == 0 && hi == 0)                                                       \
      out[(b0 + b32) * N_OUT + o] = red[(MT) & 1][pairId][0][b32]                  \
                                  + red[(MT) & 1][pairId][1][b32] + bias_o;        \
  }

// Block = 4 waves = 2 pairs. Pair: (o, 512-row run). Wave: A = Wq~ rows for its
// 64-i half, stationary in regs (72 VGPR); streams 16 m-tiles of 32 x-rows.
template<int PREP>
__global__ __launch_bounds__(256, 2) void quad2(
    const float* __restrict__ x, const float* __restrict__ W,
    const __bf16* __restrict__ xq, const __bf16* __restrict__ Wq,
    const float* __restrict__ bias, float* __restrict__ out)
{
    __shared__ float red[2][2][2][32];   // [buf][pair][sub][b]

    const int tid  = threadIdx.x;
    const int lane = tid & 63;
    const int wave = tid >> 6;
    const int pairId = wave >> 1, sub = wave & 1;   // sub: i-half (0: i<64, 1: i>=64)
    const int b32 = lane & 31, hi = lane >> 5;

    // XCD-aware bijective swizzle (512 % 8 == 0): o varies fastest within an XCD
    const int bid = blockIdx.x;
    const int swz = (bid & 7) * 64 + (bid >> 3);
    const int o  = swz & 31;
    const int mc = swz >> 5;                         // 0..15
    const long rbase = ((long)mc * 2 + pairId) * 512;

    const float bias_o = bias[o];

    // ---- stationary A fragments: Wq~[o][i][k], lane l -> row i = l&31, k = hi*8 + r ----
    bf16x8 A[2][KS_N];
    #pragma unroll
    for (int ct = 0; ct < 2; ++ct) {
        const int i = (sub * 2 + ct) * 32 + b32;
        if (PREP) {
            const __bf16* base = Wq + ((size_t)o * 128 + i) * KE + hi * 8;
            #pragma unroll
            for (int ks = 0; ks < KS_N; ++ks)
                A[ct][ks] = *reinterpret_cast<const bf16x8*>(base + ks * 16);
        } else {
            const float* wr = W + (size_t)o * WROW + (size_t)i * K129;
            #pragma unroll
            for (int ks = 0; ks < 8; ++ks) {
                bf16x8 f;
                #pragma unroll
                for (int r = 0; r < 8; ++r) f[r] = (__bf16)wr[ks * 16 + hi * 8 + r];
                A[ct][ks] = f;
            }
            bf16x8 f;
            #pragma unroll
            for (int r = 0; r < 8; ++r) f[r] = (__bf16)0.f;
            if (hi == 0) f[0] = (__bf16)wr[128];     // wlin at k=128
            A[ct][8] = f;
        }
    }

    bf16x8 Bf0[KS_N], Bf1[KS_N];
    bf16x4 Xe0[2][4], Xe1[2][4];

    load_tile<PREP>(Bf0, Xe0, xq, x, rbase + b32, sub, hi);

    for (int mt2 = 0; mt2 < 8; ++mt2) {
        STEP(mt2 * 2,     Bf0, Xe0, Bf1, Xe1);
        STEP(mt2 * 2 + 1, Bf1, Xe1, Bf0, Xe0);
    }
}

extern "C" void kernel_launch(void* const* d_in, const int* in_sizes, int n_in,
                              void* d_out, int out_size, void* d_ws, size_t ws_size,
                              hipStream_t stream) {
    const float* x    = (const float*)d_in[0];
    const float* W    = (const float*)d_in[1];
    const float* bias = (const float*)d_in[2];
    float* out = (float*)d_out;

    const size_t need = (size_t)(XQ_ELEMS + WQ_ELEMS) * sizeof(__bf16);  // ~5.9 MB
    if (ws_size >= need) {
        __bf16* xq = (__bf16*)d_ws;
        __bf16* Wq = xq + XQ_ELEMS;
        prep_x<<<1024, 256, 0, stream>>>(x, xq);
        prep_w<<<512,  256, 0, stream>>>(W, Wq);
        quad2<1><<<512, 256, 0, stream>>>(x, W, xq, Wq, bias, out);
    } else {
        quad2<0><<<512, 256, 0, stream>>>(x, W, (const __bf16*)nullptr,
                                          (const __bf16*)nullptr, bias, out);
    }
}